// Round 1
// baseline (148.896 us; speedup 1.0000x reference)
//
#include <hip/hip_runtime.h>

// ConvAttention2d: B=4, DIM=384, HEADS=8, DH=64, INNER=512, H=W=56, KS=3
// fp32 in/out. Internals: bf16 MFMA GEMMs (fp32 accum), blocked bf16 buffers.
// qkv = x @ [Wq;Wkv] -> 3x3 neighborhood attention -> out = ao @ Wo + bo
// R12: gemm1/gemm3 staging converted from reg-staged (uint4->VGPR->ds_write,
// 2 barriers/K-step) to double-buffered global_load_lds width=16 (1 barrier
// per K-step, prefetch of tile kb+1 in flight across MFMA of tile kb).
// LDS dest is wave-uniform base + lane*16 (t*8 ushorts) -> legal gload_lds.
// natt2 / cvtT_x / cvt_w unchanged from R11.

#define HW 3136
#define WIMG 56
#define QKV_CH 1536
#define SCALE 0.125f
#define SLEN 200   // natt LDS row stride (ushorts)

typedef __bf16 bf16x8_t __attribute__((ext_vector_type(8)));
typedef float f32x4_t __attribute__((ext_vector_type(4)));

__device__ __forceinline__ float bf2f(unsigned short u) {
    return __uint_as_float(((unsigned int)u) << 16);
}
__device__ __forceinline__ unsigned short f2bf(float f) {
    unsigned int u = __float_as_uint(f);
    u += 0x7FFFu + ((u >> 16) & 1u);   // round-to-nearest-even
    return (unsigned short)(u >> 16);
}

// async global->LDS, 16B per lane. LDS dest must be wave-uniform base +
// lane*16; global src is per-lane.
__device__ __forceinline__ void gll16(const unsigned short* g, unsigned short* l) {
    __builtin_amdgcn_global_load_lds(
        (const __attribute__((address_space(1))) unsigned int*)g,
        (__attribute__((address_space(3))) unsigned int*)l,
        16, 0, 0);
}

// ---------------------------------------------------------------------------
// Weights f32 -> bf16, both blocked:
//   wT  [oblk12][kb12][128o][32k]  for gemm1 (Wq||Wkv, K=384)
//   wT3 [oblk3][kb16][128o][32k]   for gemm3 (Wo, K=512)
// Thread = one uint4 (8 source floats). 73728 + 24576 = 98304 = 384 blocks.
// ---------------------------------------------------------------------------
__global__ __launch_bounds__(256) void cvt_w(
    const float* __restrict__ Wq, const float* __restrict__ Wkv,
    const float* __restrict__ Wo,
    unsigned short* __restrict__ wT, unsigned short* __restrict__ wT3)
{
    const int i = blockIdx.x * 256 + threadIdx.x;
    if (i < 73728) {                    // wT: 12*12*128*4 uint4 slots
        const int g = i & 3;
        const int idx3 = i >> 2;        // [oblk][kb][o128]
        const int o128 = idx3 & 127;
        const int rest = idx3 >> 7;     // 0..143
        const int kb = rest % 12, oblk = rest / 12;
        const int o = oblk * 128 + o128;
        const int k0 = kb * 32 + g * 8;
        const float* src = (o < 512) ? (Wq + (size_t)o * 384 + k0)
                                     : (Wkv + (size_t)(o - 512) * 384 + k0);
        const float4 v0 = *reinterpret_cast<const float4*>(src);
        const float4 v1 = *reinterpret_cast<const float4*>(src + 4);
        uint4 u;
        u.x = (unsigned int)f2bf(v0.x) | ((unsigned int)f2bf(v0.y) << 16);
        u.y = (unsigned int)f2bf(v0.z) | ((unsigned int)f2bf(v0.w) << 16);
        u.z = (unsigned int)f2bf(v1.x) | ((unsigned int)f2bf(v1.y) << 16);
        u.w = (unsigned int)f2bf(v1.z) | ((unsigned int)f2bf(v1.w) << 16);
        reinterpret_cast<uint4*>(wT)[i] = u;
    } else {                            // wT3: 3*16*128*4 = 24576 uint4 slots
        const int j = i - 73728;        // [0, 24576)
        const int g = j & 3;
        const int idx3 = j >> 2;        // 0..6143
        const int o128 = idx3 & 127;
        const int rest = idx3 >> 7;     // 0..47
        const int kb = rest % 16, oblk = rest / 16;
        const int o = oblk * 128 + o128;            // < 384
        const float* src = Wo + (size_t)o * 512 + kb * 32 + g * 8;
        const float4 v0 = *reinterpret_cast<const float4*>(src);
        const float4 v1 = *reinterpret_cast<const float4*>(src + 4);
        uint4 u;
        u.x = (unsigned int)f2bf(v0.x) | ((unsigned int)f2bf(v0.y) << 16);
        u.y = (unsigned int)f2bf(v0.z) | ((unsigned int)f2bf(v0.w) << 16);
        u.z = (unsigned int)f2bf(v1.x) | ((unsigned int)f2bf(v1.y) << 16);
        u.w = (unsigned int)f2bf(v1.z) | ((unsigned int)f2bf(v1.w) << 16);
        reinterpret_cast<uint4*>(wT3)[j] = u;
    }
}

// ---------------------------------------------------------------------------
// x (b,c,s) f32 -> blocked bf16 xT[b][sblk25][kb12][128s][32k], s padded to
// 3200 (tail zero-filled). Unchanged.
// ---------------------------------------------------------------------------
__global__ __launch_bounds__(256) void cvtT_x(
    const float* __restrict__ x, unsigned short* __restrict__ xT)
{
    __shared__ unsigned short Tl[64 * 36];   // [s][c], pad 36
    const int sblk = blockIdx.x, kblk = blockIdx.y, b = blockIdx.z;
    const int t = threadIdx.x;

    if (sblk == 49) {                   // zero-fill s in [3136,3200)
        unsigned short* dst = xT + (((size_t)b * 25 + 24) * 12 + kblk) * 4096 + 2048;
        *reinterpret_cast<uint4*>(dst + t * 8) = (uint4){0, 0, 0, 0};
        return;
    }

    const float* xp = x + ((size_t)b * 384 + (size_t)kblk * 32) * HW + sblk * 64;
    const int c = t >> 3;                    // 0..31
#pragma unroll
    for (int i = 0; i < 2; i++) {
        const int sc = (t & 7) + 8 * i;      // 0..15 (float4 chunks)
        const float4 v = *reinterpret_cast<const float4*>(xp + (size_t)c * HW + sc * 4);
        const int s4 = sc * 4;
        Tl[(s4 + 0) * 36 + c] = f2bf(v.x);
        Tl[(s4 + 1) * 36 + c] = f2bf(v.y);
        Tl[(s4 + 2) * 36 + c] = f2bf(v.z);
        Tl[(s4 + 3) * 36 + c] = f2bf(v.w);
    }
    __syncthreads();

    const int row = t >> 2, gran = t & 3;
    const uint2 lo = *reinterpret_cast<const uint2*>(&Tl[row * 36 + gran * 8]);
    const uint2 hi = *reinterpret_cast<const uint2*>(&Tl[row * 36 + gran * 8 + 4]);
    uint4 o; o.x = lo.x; o.y = lo.y; o.z = hi.x; o.w = hi.y;
    unsigned short* dst = xT + (((size_t)b * 25 + (sblk >> 1)) * 12 + kblk) * 4096
                        + (sblk & 1) * 2048;
    *reinterpret_cast<uint4*>(dst + t * 8) = o;
}

// ---------------------------------------------------------------------------
// GEMM1 (R12): tile 128o x 128s, BK=32, double-buffered global_load_lds
// staging (4x 16B issues/thread/K-step), 1 barrier per K-step, 16 MFMA/wave.
// grid (25, 12, 4). Same per-output K-order as R11 -> bit-exact.
// ---------------------------------------------------------------------------
__global__ __launch_bounds__(256) void gemm1(
    const unsigned short* __restrict__ xT,   // [b][25][12][128][32]
    const unsigned short* __restrict__ wT,   // [12][12][128][32]
    unsigned short* __restrict__ qkv)        // (4,1536,3136) bf16
{
    __shared__ __align__(16) unsigned short A_lds[2][128 * 32];
    __shared__ __align__(16) unsigned short B_lds[2][128 * 32];

    const int sblk = blockIdx.x;             // 0..24
    const int oblk = blockIdx.y;             // 0..11
    const int b  = blockIdx.z;
    const int t  = threadIdx.x;
    const int lane = t & 63, w = t >> 6;
    const int quad = lane >> 4, mrow = lane & 15;
    const int wm = w >> 1, wn = w & 1;       // wave quadrant

    const unsigned short* wsrc = wT + ((size_t)oblk * 12) * 4096;
    const unsigned short* xsrc = xT + (((size_t)b * 25 + sblk) * 12) * 4096;

    f32x4_t acc[4][4];
#pragma unroll
    for (int m = 0; m < 4; m++)
#pragma unroll
        for (int n = 0; n < 4; n++) acc[m][n] = (f32x4_t){0.f, 0.f, 0.f, 0.f};

    // prologue: stage tile kb=0 into buffer 0
    gll16(wsrc + t * 8,        &A_lds[0][t * 8]);
    gll16(wsrc + 2048 + t * 8, &A_lds[0][2048 + t * 8]);
    gll16(xsrc + t * 8,        &B_lds[0][t * 8]);
    gll16(xsrc + 2048 + t * 8, &B_lds[0][2048 + t * 8]);
    __syncthreads();                         // drains vmcnt(0): buf0 ready

    int cur = 0;
    for (int kb = 0; kb < 12; kb++) {
        if (kb + 1 < 12) {                   // prefetch next tile into cur^1
            const unsigned short* as = wsrc + (size_t)(kb + 1) * 4096;
            const unsigned short* bs = xsrc + (size_t)(kb + 1) * 4096;
            const int nxt = cur ^ 1;
            gll16(as + t * 8,        &A_lds[nxt][t * 8]);
            gll16(as + 2048 + t * 8, &A_lds[nxt][2048 + t * 8]);
            gll16(bs + t * 8,        &B_lds[nxt][t * 8]);
            gll16(bs + 2048 + t * 8, &B_lds[nxt][2048 + t * 8]);
        }

        bf16x8_t af[4], bfr[4];
#pragma unroll
        for (int m = 0; m < 4; m++)
            af[m] = *reinterpret_cast<const bf16x8_t*>(&A_lds[cur][(wm * 64 + m * 16 + mrow) * 32 + quad * 8]);
#pragma unroll
        for (int n = 0; n < 4; n++)
            bfr[n] = *reinterpret_cast<const bf16x8_t*>(&B_lds[cur][(wn * 64 + n * 16 + mrow) * 32 + quad * 8]);
#pragma unroll
        for (int m = 0; m < 4; m++)
#pragma unroll
            for (int n = 0; n < 4; n++)
                acc[m][n] = __builtin_amdgcn_mfma_f32_16x16x32_bf16(af[m], bfr[n], acc[m][n], 0, 0, 0);

        __syncthreads();                     // drains prefetch vmcnt + lgkm
        cur ^= 1;
    }

    const int o0 = oblk * 128 + wm * 64;
    const int s0 = sblk * 128 + wn * 64;
    unsigned short* outb = qkv + (size_t)b * QKV_CH * HW;
#pragma unroll
    for (int m = 0; m < 4; m++)
#pragma unroll
        for (int n = 0; n < 4; n++) {
            const int ss = s0 + n * 16 + mrow;
            if (ss < HW) {
#pragma unroll
                for (int r = 0; r < 4; r++) {
                    const int oo = o0 + m * 16 + quad * 4 + r;
                    outb[(size_t)oo * HW + ss] = f2bf(acc[m][n][r]);
                }
            }
        }
}

// ---------------------------------------------------------------------------
// Neighborhood attention v3: unchanged from R11.
// ---------------------------------------------------------------------------
__global__ __launch_bounds__(256) void natt2(
    const unsigned short* __restrict__ qkv,  // (4,1536,3136) bf16
    unsigned short* __restrict__ aoT)        // [4][49][16][64][32] bf16
{
    __shared__ __align__(16) unsigned short smem[2 * 64 * SLEN]; // Kl | Vl
    unsigned short* Kl = smem;
    unsigned short* Vl = smem + 64 * SLEN;
    float* dred = reinterpret_cast<float*>(smem);  // overlays Kl after dots

    const int t = threadIdx.x, lane = t & 63, w = t >> 6;
    const int sblk = blockIdx.x;
    const int s0 = sblk * 64;
    const int s  = s0 + lane;
    const int h  = blockIdx.y, b = blockIdx.z;
    const int y  = s / WIMG, xx = s % WIMG;

    const size_t hbase = (size_t)b * QKV_CH * HW + (size_t)(h * 64) * HW;
    const unsigned short* kg = qkv + hbase + (size_t)512 * HW;
    const unsigned short* vg = qkv + hbase + (size_t)1024 * HW;

#pragma unroll
    for (int i = 0; i < 6; i++) {
        const int f = i * 256 + t;        // 0..1535
        const int d = f / 24, j = f % 24;
        int g = s0 - 64 + j * 8;
        g = min(max(g, 0), HW - 8);       // clamped slots only read by masked taps
        const uint4 k4 = *reinterpret_cast<const uint4*>(kg + (size_t)d * HW + g);
        const uint4 v4 = *reinterpret_cast<const uint4*>(vg + (size_t)d * HW + g);
        *reinterpret_cast<uint4*>(&Kl[d * SLEN + j * 8]) = k4;
        *reinterpret_cast<uint4*>(&Vl[d * SLEN + j * 8]) = v4;
    }

    int   off9[9];
    float msk[9];
#pragma unroll
    for (int ty = 0; ty < 3; ty++)
#pragma unroll
        for (int tx = 0; tx < 3; tx++) {
            const int tap = ty * 3 + tx;
            const int ny = y + ty - 1, nx = xx + tx - 1;
            const bool v = (ny >= 0) && (ny < WIMG) && (nx >= 0) && (nx < WIMG);
            off9[tap] = v ? ((ty - 1) * WIMG + (tx - 1)) : 0;
            msk[tap]  = v ? 1.f : 0.f;
        }

    __syncthreads();

    const unsigned short* qp = qkv + hbase + s;
    float dots[9];
#pragma unroll
    for (int tp = 0; tp < 9; tp++) dots[tp] = 0.f;
#pragma unroll 4
    for (int dd = 0; dd < 16; dd++) {
        const int d = w * 16 + dd;
        const float qv = bf2f(qp[(size_t)d * HW]);
        const int bi = d * SLEN + lane + 64;
#pragma unroll
        for (int tp = 0; tp < 9; tp++)
            dots[tp] += qv * bf2f(Kl[bi + off9[tp]]);
    }

    __syncthreads();
#pragma unroll
    for (int tp = 0; tp < 9; tp++) dred[(tp * 4 + w) * 64 + lane] = dots[tp];
    __syncthreads();

    float mx = -1e30f, dt[9];
#pragma unroll
    for (int tp = 0; tp < 9; tp++) {
        const float sum = dred[(tp * 4 + 0) * 64 + lane] + dred[(tp * 4 + 1) * 64 + lane] +
                          dred[(tp * 4 + 2) * 64 + lane] + dred[(tp * 4 + 3) * 64 + lane];
        dt[tp] = msk[tp] * (sum * SCALE);
        mx = fmaxf(mx, dt[tp]);
    }
    float se = 0.f, w9[9];
#pragma unroll
    for (int tp = 0; tp < 9; tp++) { w9[tp] = __expf(dt[tp] - mx); se += w9[tp]; }
    const float inv = 1.f / se;
#pragma unroll
    for (int tp = 0; tp < 9; tp++) w9[tp] *= inv * msk[tp];

    __align__(16) unsigned short ov[16];
#pragma unroll 4
    for (int dd = 0; dd < 16; dd++) {
        const int d = w * 16 + dd;
        const int bi = d * SLEN + lane + 64;
        float o = 0.f;
#pragma unroll
        for (int tp = 0; tp < 9; tp++)
            o += w9[tp] * bf2f(Vl[bi + off9[tp]]);
        ov[dd] = f2bf(o);
    }
    // blocked store: tile (b, sblk, kb=h*2+(w>>1)), row=lane, col=(w&1)*16
    unsigned short* dst = aoT + (((size_t)(b * 49 + sblk)) * 16 + (h * 2 + (w >> 1))) * 2048
                        + lane * 32 + (w & 1) * 16;
    *reinterpret_cast<uint4*>(dst)     = *reinterpret_cast<const uint4*>(ov);
    *reinterpret_cast<uint4*>(dst + 8) = *reinterpret_cast<const uint4*>(ov + 8);
}

// ---------------------------------------------------------------------------
// GEMM3 (R12): tile 128o x 64s, BK=32, double-buffered global_load_lds
// staging (3x 16B issues/thread/K-step), 1 barrier per K-step, 8 MFMA/wave.
// grid (49, 3, 4). Per-output K-order identical -> bit-exact.
// ---------------------------------------------------------------------------
__global__ __launch_bounds__(256) void gemm3(
    const unsigned short* __restrict__ aoT,  // [4][49][16][64][32]
    const unsigned short* __restrict__ wT3,  // [3][16][128][32]
    const float* __restrict__ bias,          // (384)
    float* __restrict__ out)                 // (4,384,3136) f32
{
    __shared__ __align__(16) unsigned short A_lds[2][128 * 32];
    __shared__ __align__(16) unsigned short B_lds[2][64 * 32];

    const int sblk = blockIdx.x;             // 0..48
    const int oblk = blockIdx.y;             // 0..2
    const int b  = blockIdx.z;
    const int t  = threadIdx.x;
    const int lane = t & 63, w = t >> 6;
    const int quad = lane >> 4, mrow = lane & 15;
    const int wm = w >> 1, wn = w & 1;       // wave: 64o x 32s quadrant

    const unsigned short* asrc = wT3 + (size_t)oblk * 16 * 4096;
    const unsigned short* bsrc = aoT + ((size_t)(b * 49 + sblk)) * 16 * 2048;

    f32x4_t acc[4][2];
#pragma unroll
    for (int m = 0; m < 4; m++)
#pragma unroll
        for (int n = 0; n < 2; n++) acc[m][n] = (f32x4_t){0.f, 0.f, 0.f, 0.f};

    // prologue: stage tile kb=0 into buffer 0
    gll16(asrc + t * 8,        &A_lds[0][t * 8]);
    gll16(asrc + 2048 + t * 8, &A_lds[0][2048 + t * 8]);
    gll16(bsrc + t * 8,        &B_lds[0][t * 8]);
    __syncthreads();

    int cur = 0;
    for (int kb = 0; kb < 16; kb++) {
        if (kb + 1 < 16) {
            const unsigned short* as = asrc + (size_t)(kb + 1) * 4096;
            const unsigned short* bs = bsrc + (size_t)(kb + 1) * 2048;
            const int nxt = cur ^ 1;
            gll16(as + t * 8,        &A_lds[nxt][t * 8]);
            gll16(as + 2048 + t * 8, &A_lds[nxt][2048 + t * 8]);
            gll16(bs + t * 8,        &B_lds[nxt][t * 8]);
        }

        bf16x8_t af[4], bfr[2];
#pragma unroll
        for (int m = 0; m < 4; m++)
            af[m] = *reinterpret_cast<const bf16x8_t*>(&A_lds[cur][(wm * 64 + m * 16 + mrow) * 32 + quad * 8]);
#pragma unroll
        for (int n = 0; n < 2; n++)
            bfr[n] = *reinterpret_cast<const bf16x8_t*>(&B_lds[cur][(wn * 32 + n * 16 + mrow) * 32 + quad * 8]);
#pragma unroll
        for (int m = 0; m < 4; m++)
#pragma unroll
            for (int n = 0; n < 2; n++)
                acc[m][n] = __builtin_amdgcn_mfma_f32_16x16x32_bf16(af[m], bfr[n], acc[m][n], 0, 0, 0);

        __syncthreads();
        cur ^= 1;
    }

    const int o0 = oblk * 128 + wm * 64;
    const int s0 = sblk * 64 + wn * 32;
    float* outb = out + (size_t)b * 384 * HW;
#pragma unroll
    for (int m = 0; m < 4; m++)
#pragma unroll
        for (int n = 0; n < 2; n++) {
            const int ss = s0 + n * 16 + mrow;      // < 3136 always (49*64 exact)
#pragma unroll
            for (int r = 0; r < 4; r++) {
                const int oo = o0 + m * 16 + quad * 4 + r;
                outb[(size_t)oo * HW + ss] = acc[m][n][r] + bias[oo];
            }
        }
}

extern "C" void kernel_launch(void* const* d_in, const int* in_sizes, int n_in,
                              void* d_out, int out_size, void* d_ws, size_t ws_size,
                              hipStream_t stream) {
    const float* x   = (const float*)d_in[0];
    const float* Wq  = (const float*)d_in[1];
    const float* Wkv = (const float*)d_in[2];
    const float* Wo  = (const float*)d_in[3];
    const float* bo  = (const float*)d_in[4];
    float* out = (float*)d_out;

    // ws layout (bf16 elements)
    unsigned short* xT   = (unsigned short*)d_ws;                 // 4*25*12*4096 = 4,915,200
    unsigned short* wT   = xT + (size_t)4915200;                  // 12*12*128*32 =   589,824
    unsigned short* wT3  = wT + (size_t)589824;                   // 3*16*128*32  =   196,608
    unsigned short* qkvb = wT3 + (size_t)196608;                  // 4*1536*3136  = 19,267,584
    unsigned short* aoT  = qkvb + (size_t)4 * QKV_CH * HW;        // 4*49*16*2048 =  6,422,528

    cvt_w<<<dim3(384), 256, 0, stream>>>(Wq, Wkv, Wo, wT, wT3);   // exact: 98304 threads
    cvtT_x<<<dim3(50, 12, 4), 256, 0, stream>>>(x, xT);

    gemm1<<<dim3(25, 12, 4), 256, 0, stream>>>(xT, wT, qkvb);
    natt2<<<dim3(49, 8, 4), 256, 0, stream>>>(qkvb, aoT);
    gemm3<<<dim3(49, 3, 4), 256, 0, stream>>>(aoT, wT3, bo, out);
}

// Round 2
// 145.699 us; speedup vs baseline: 1.0219x; 1.0219x over previous
//
#include <hip/hip_runtime.h>

// ConvAttention2d: B=4, DIM=384, HEADS=8, DH=64, INNER=512, H=W=56, KS=3
// fp32 in/out. Internals: bf16 MFMA GEMMs (fp32 accum), blocked bf16 buffers.
// qkv = x @ [Wq;Wkv] -> 3x3 neighborhood attention -> out = ao @ Wo + bo
// R13: qkv intermediate re-laid-out as [which][b][head][s][d] (s-major rows).
//  - gemm1: R11 staging structure (measured best) + new epilogue writing
//    [s][d] rows via packed dwordx2 stores (16 stores/thread vs 64 scalar).
//  - natt2: rewritten with [s][d] LDS tiles (stride 72 ush = 144B, 16B-aligned
//    rows, bank-uniform). dots/PV use ds_read_b128 (18 each) instead of 144
//    scalar ds_read_u16. Accumulation order per output preserved -> bit-exact.
//  - gemm3 / cvt_w / cvtT_x: R11 verbatim.

#define HW 3136
#define WIMG 56
#define QKV_CH 1536
#define SCALE 0.125f
#define KSTR 72            // natt LDS row stride in ushorts (144B, 36 dwords)
#define NROWS 180          // staged rows: s0-59 .. s0+120
#define QKV_T 6422528      // one tensor: 4*8*3136*64 bf16 elems

typedef __bf16 bf16x8_t __attribute__((ext_vector_type(8)));
typedef float f32x4_t __attribute__((ext_vector_type(4)));
typedef unsigned short ushort8 __attribute__((ext_vector_type(8)));

__device__ __forceinline__ float bf2f(unsigned short u) {
    return __uint_as_float(((unsigned int)u) << 16);
}
__device__ __forceinline__ unsigned short f2bf(float f) {
    unsigned int u = __float_as_uint(f);
    u += 0x7FFFu + ((u >> 16) & 1u);   // round-to-nearest-even
    return (unsigned short)(u >> 16);
}

// ---------------------------------------------------------------------------
// Weights f32 -> bf16, both blocked (unchanged):
//   wT  [oblk12][kb12][128o][32k]  for gemm1 (Wq||Wkv, K=384)
//   wT3 [oblk3][kb16][128o][32k]   for gemm3 (Wo, K=512)
// ---------------------------------------------------------------------------
__global__ __launch_bounds__(256) void cvt_w(
    const float* __restrict__ Wq, const float* __restrict__ Wkv,
    const float* __restrict__ Wo,
    unsigned short* __restrict__ wT, unsigned short* __restrict__ wT3)
{
    const int i = blockIdx.x * 256 + threadIdx.x;
    if (i < 73728) {                    // wT: 12*12*128*4 uint4 slots
        const int g = i & 3;
        const int idx3 = i >> 2;        // [oblk][kb][o128]
        const int o128 = idx3 & 127;
        const int rest = idx3 >> 7;     // 0..143
        const int kb = rest % 12, oblk = rest / 12;
        const int o = oblk * 128 + o128;
        const int k0 = kb * 32 + g * 8;
        const float* src = (o < 512) ? (Wq + (size_t)o * 384 + k0)
                                     : (Wkv + (size_t)(o - 512) * 384 + k0);
        const float4 v0 = *reinterpret_cast<const float4*>(src);
        const float4 v1 = *reinterpret_cast<const float4*>(src + 4);
        uint4 u;
        u.x = (unsigned int)f2bf(v0.x) | ((unsigned int)f2bf(v0.y) << 16);
        u.y = (unsigned int)f2bf(v0.z) | ((unsigned int)f2bf(v0.w) << 16);
        u.z = (unsigned int)f2bf(v1.x) | ((unsigned int)f2bf(v1.y) << 16);
        u.w = (unsigned int)f2bf(v1.z) | ((unsigned int)f2bf(v1.w) << 16);
        reinterpret_cast<uint4*>(wT)[i] = u;
    } else {                            // wT3: 3*16*128*4 = 24576 uint4 slots
        const int j = i - 73728;        // [0, 24576)
        const int g = j & 3;
        const int idx3 = j >> 2;        // 0..6143
        const int o128 = idx3 & 127;
        const int rest = idx3 >> 7;     // 0..47
        const int kb = rest % 16, oblk = rest / 16;
        const int o = oblk * 128 + o128;            // < 384
        const float* src = Wo + (size_t)o * 512 + kb * 32 + g * 8;
        const float4 v0 = *reinterpret_cast<const float4*>(src);
        const float4 v1 = *reinterpret_cast<const float4*>(src + 4);
        uint4 u;
        u.x = (unsigned int)f2bf(v0.x) | ((unsigned int)f2bf(v0.y) << 16);
        u.y = (unsigned int)f2bf(v0.z) | ((unsigned int)f2bf(v0.w) << 16);
        u.z = (unsigned int)f2bf(v1.x) | ((unsigned int)f2bf(v1.y) << 16);
        u.w = (unsigned int)f2bf(v1.z) | ((unsigned int)f2bf(v1.w) << 16);
        reinterpret_cast<uint4*>(wT3)[j] = u;
    }
}

// ---------------------------------------------------------------------------
// x (b,c,s) f32 -> blocked bf16 xT[b][sblk25][kb12][128s][32k] (unchanged).
// ---------------------------------------------------------------------------
__global__ __launch_bounds__(256) void cvtT_x(
    const float* __restrict__ x, unsigned short* __restrict__ xT)
{
    __shared__ unsigned short Tl[64 * 36];   // [s][c], pad 36
    const int sblk = blockIdx.x, kblk = blockIdx.y, b = blockIdx.z;
    const int t = threadIdx.x;

    if (sblk == 49) {                   // zero-fill s in [3136,3200)
        unsigned short* dst = xT + (((size_t)b * 25 + 24) * 12 + kblk) * 4096 + 2048;
        *reinterpret_cast<uint4*>(dst + t * 8) = (uint4){0, 0, 0, 0};
        return;
    }

    const float* xp = x + ((size_t)b * 384 + (size_t)kblk * 32) * HW + sblk * 64;
    const int c = t >> 3;                    // 0..31
#pragma unroll
    for (int i = 0; i < 2; i++) {
        const int sc = (t & 7) + 8 * i;      // 0..15 (float4 chunks)
        const float4 v = *reinterpret_cast<const float4*>(xp + (size_t)c * HW + sc * 4);
        const int s4 = sc * 4;
        Tl[(s4 + 0) * 36 + c] = f2bf(v.x);
        Tl[(s4 + 1) * 36 + c] = f2bf(v.y);
        Tl[(s4 + 2) * 36 + c] = f2bf(v.z);
        Tl[(s4 + 3) * 36 + c] = f2bf(v.w);
    }
    __syncthreads();

    const int row = t >> 2, gran = t & 3;
    const uint2 lo = *reinterpret_cast<const uint2*>(&Tl[row * 36 + gran * 8]);
    const uint2 hi = *reinterpret_cast<const uint2*>(&Tl[row * 36 + gran * 8 + 4]);
    uint4 o; o.x = lo.x; o.y = lo.y; o.z = hi.x; o.w = hi.y;
    unsigned short* dst = xT + (((size_t)b * 25 + (sblk >> 1)) * 12 + kblk) * 4096
                        + (sblk & 1) * 2048;
    *reinterpret_cast<uint4*>(dst + t * 8) = o;
}

// ---------------------------------------------------------------------------
// GEMM1 (R13): R11 staging/compute (identity uint4 staging, 2 barriers/K-step,
// 16 MFMA/wave). New epilogue: write qkvT[which][b][h][s][64] rows with
// packed dwordx2 stores. grid (25, 12, 4).
// ---------------------------------------------------------------------------
__global__ __launch_bounds__(256) void gemm1(
    const unsigned short* __restrict__ xT,   // [b][25][12][128][32]
    const unsigned short* __restrict__ wT,   // [12][12][128][32]
    unsigned short* __restrict__ qkvT)       // [3][4][8][3136][64] bf16
{
    __shared__ __align__(16) unsigned short A_lds[128 * 32];
    __shared__ __align__(16) unsigned short B_lds[128 * 32];

    const int sblk = blockIdx.x;             // 0..24
    const int oblk = blockIdx.y;             // 0..11
    const int b  = blockIdx.z;
    const int t  = threadIdx.x;
    const int lane = t & 63, w = t >> 6;
    const int quad = lane >> 4, mrow = lane & 15;
    const int wm = w >> 1, wn = w & 1;       // wave quadrant

    const unsigned short* wsrc = wT + ((size_t)oblk * 12) * 4096;
    const unsigned short* xsrc = xT + (((size_t)b * 25 + sblk) * 12) * 4096;

    f32x4_t acc[4][4];
#pragma unroll
    for (int m = 0; m < 4; m++)
#pragma unroll
        for (int n = 0; n < 4; n++) acc[m][n] = (f32x4_t){0.f, 0.f, 0.f, 0.f};

    for (int kb = 0; kb < 12; kb++) {
        const uint4 a0 = *reinterpret_cast<const uint4*>(wsrc + (size_t)kb * 4096 + t * 8);
        const uint4 a1 = *reinterpret_cast<const uint4*>(wsrc + (size_t)kb * 4096 + 2048 + t * 8);
        const uint4 b0 = *reinterpret_cast<const uint4*>(xsrc + (size_t)kb * 4096 + t * 8);
        const uint4 b1 = *reinterpret_cast<const uint4*>(xsrc + (size_t)kb * 4096 + 2048 + t * 8);

        __syncthreads();   // previous iteration's fragment reads complete
        *reinterpret_cast<uint4*>(A_lds + t * 8) = a0;
        *reinterpret_cast<uint4*>(A_lds + 2048 + t * 8) = a1;
        *reinterpret_cast<uint4*>(B_lds + t * 8) = b0;
        *reinterpret_cast<uint4*>(B_lds + 2048 + t * 8) = b1;
        __syncthreads();

        bf16x8_t af[4], bf[4];
#pragma unroll
        for (int m = 0; m < 4; m++)
            af[m] = *reinterpret_cast<const bf16x8_t*>(&A_lds[(wm * 64 + m * 16 + mrow) * 32 + quad * 8]);
#pragma unroll
        for (int n = 0; n < 4; n++)
            bf[n] = *reinterpret_cast<const bf16x8_t*>(&B_lds[(wn * 64 + n * 16 + mrow) * 32 + quad * 8]);
#pragma unroll
        for (int m = 0; m < 4; m++)
#pragma unroll
            for (int n = 0; n < 4; n++)
                acc[m][n] = __builtin_amdgcn_mfma_f32_16x16x32_bf16(af[m], bf[n], acc[m][n], 0, 0, 0);
    }

    // epilogue: oo = oblk*128 + wm*64 + m*16 + quad*4 + r
    //   which = oblk>>2 (0=q,1=k,2=v), head = (oblk&3)*2 + wm, d = m*16+quad*4+r
    const int which = oblk >> 2;
    const int hq = (oblk & 3) * 2 + wm;
    const int s0 = sblk * 128 + wn * 64;
    unsigned short* outb = qkvT + (size_t)which * QKV_T
                         + ((size_t)(b * 8 + hq) * HW) * 64;
#pragma unroll
    for (int m = 0; m < 4; m++) {
        const int d0 = m * 16 + quad * 4;
#pragma unroll
        for (int n = 0; n < 4; n++) {
            const int ss = s0 + n * 16 + mrow;
            if (ss < HW) {
                uint2 u;
                u.x = (unsigned int)f2bf(acc[m][n][0]) | ((unsigned int)f2bf(acc[m][n][1]) << 16);
                u.y = (unsigned int)f2bf(acc[m][n][2]) | ((unsigned int)f2bf(acc[m][n][3]) << 16);
                *reinterpret_cast<uint2*>(outb + (size_t)ss * 64 + d0) = u;
            }
        }
    }
}

// ---------------------------------------------------------------------------
// Neighborhood attention (R13): [s][d] LDS tiles, vectorized b128 reads.
// Thread (w,lane): position s0+lane, channels d = w*16 .. w*16+15.
// LDS rows 0..179 <-> s = s0-59 .. s0+120 (clamped staging; masked taps
// multiply by 0). Row stride 72 ush = 144B: 16B-aligned, bank-uniform.
// Accumulation order per output element identical to R11 -> bit-exact.
// ---------------------------------------------------------------------------
__global__ __launch_bounds__(256) void natt2(
    const unsigned short* __restrict__ qkvT, // [3][4][8][3136][64] bf16
    unsigned short* __restrict__ aoT)        // [4][49][16][64][32] bf16
{
    __shared__ __align__(16) unsigned short smem[2 * NROWS * KSTR]; // Kl | Vl
    unsigned short* Kl = smem;
    unsigned short* Vl = smem + NROWS * KSTR;
    float* dred = reinterpret_cast<float*>(smem);  // overlays Kl after dots

    const int t = threadIdx.x, lane = t & 63, w = t >> 6;
    const int sblk = blockIdx.x;
    const int s0 = sblk * 64;
    const int s  = s0 + lane;
    const int h  = blockIdx.y, b = blockIdx.z;
    const int y  = s / WIMG, xx = s % WIMG;

    const unsigned short* qg = qkvT + ((size_t)(b * 8 + h) * HW) * 64;
    const unsigned short* kg = qg + (size_t)QKV_T;
    const unsigned short* vg = qg + (size_t)(2 * QKV_T);

    // stage K/V rows [s0-59, s0+120] -> 180 rows x 64 d (1440 16B chunks)
#pragma unroll
    for (int i = 0; i < 6; i++) {
        const int f = i * 256 + t;        // 0..1535, use < 1440
        if (f < NROWS * 8) {
            const int row = f >> 3, c8 = f & 7;
            int srow = s0 - 59 + row;
            srow = min(max(srow, 0), HW - 1);
            const uint4 k4 = *reinterpret_cast<const uint4*>(kg + (size_t)srow * 64 + c8 * 8);
            const uint4 v4 = *reinterpret_cast<const uint4*>(vg + (size_t)srow * 64 + c8 * 8);
            *reinterpret_cast<uint4*>(&Kl[row * KSTR + c8 * 8]) = k4;
            *reinterpret_cast<uint4*>(&Vl[row * KSTR + c8 * 8]) = v4;
        }
    }

    int   roff[9];
    float msk[9];
#pragma unroll
    for (int ty = 0; ty < 3; ty++)
#pragma unroll
        for (int tx = 0; tx < 3; tx++) {
            const int tap = ty * 3 + tx;
            const int ny = y + ty - 1, nx = xx + tx - 1;
            const bool v = (ny >= 0) && (ny < WIMG) && (nx >= 0) && (nx < WIMG);
            roff[tap] = (v ? ((ty - 1) * WIMG + (tx - 1)) : 0) * KSTR;
            msk[tap]  = v ? 1.f : 0.f;
        }

    // q: 16 channels for this (pos, w) — vectorized global
    float qv[16];
    {
        const uint4 q0 = *reinterpret_cast<const uint4*>(qg + (size_t)s * 64 + w * 16);
        const uint4 q1 = *reinterpret_cast<const uint4*>(qg + (size_t)s * 64 + w * 16 + 8);
        qv[0] = bf2f((unsigned short)(q0.x & 0xffff)); qv[1] = bf2f((unsigned short)(q0.x >> 16));
        qv[2] = bf2f((unsigned short)(q0.y & 0xffff)); qv[3] = bf2f((unsigned short)(q0.y >> 16));
        qv[4] = bf2f((unsigned short)(q0.z & 0xffff)); qv[5] = bf2f((unsigned short)(q0.z >> 16));
        qv[6] = bf2f((unsigned short)(q0.w & 0xffff)); qv[7] = bf2f((unsigned short)(q0.w >> 16));
        qv[8]  = bf2f((unsigned short)(q1.x & 0xffff)); qv[9]  = bf2f((unsigned short)(q1.x >> 16));
        qv[10] = bf2f((unsigned short)(q1.y & 0xffff)); qv[11] = bf2f((unsigned short)(q1.y >> 16));
        qv[12] = bf2f((unsigned short)(q1.z & 0xffff)); qv[13] = bf2f((unsigned short)(q1.z >> 16));
        qv[14] = bf2f((unsigned short)(q1.w & 0xffff)); qv[15] = bf2f((unsigned short)(q1.w >> 16));
    }

    __syncthreads();

    const int rbase = (59 + lane) * KSTR + w * 16;   // own row, own d-range

    float dots[9];
#pragma unroll
    for (int tp = 0; tp < 9; tp++) dots[tp] = 0.f;
#pragma unroll
    for (int hh = 0; hh < 2; hh++) {
#pragma unroll
        for (int tp = 0; tp < 9; tp++) {
            const ushort8 kk = *reinterpret_cast<const ushort8*>(&Kl[rbase + roff[tp] + hh * 8]);
#pragma unroll
            for (int j = 0; j < 8; j++)
                dots[tp] += qv[hh * 8 + j] * bf2f(kk[j]);   // dd ascending per tap
        }
    }

    __syncthreads();
#pragma unroll
    for (int tp = 0; tp < 9; tp++) dred[(tp * 4 + w) * 64 + lane] = dots[tp];
    __syncthreads();

    float mx = -1e30f, dt[9];
#pragma unroll
    for (int tp = 0; tp < 9; tp++) {
        const float sum = dred[(tp * 4 + 0) * 64 + lane] + dred[(tp * 4 + 1) * 64 + lane] +
                          dred[(tp * 4 + 2) * 64 + lane] + dred[(tp * 4 + 3) * 64 + lane];
        dt[tp] = msk[tp] * (sum * SCALE);
        mx = fmaxf(mx, dt[tp]);
    }
    float se = 0.f, w9[9];
#pragma unroll
    for (int tp = 0; tp < 9; tp++) { w9[tp] = __expf(dt[tp] - mx); se += w9[tp]; }
    const float inv = 1.f / se;
#pragma unroll
    for (int tp = 0; tp < 9; tp++) w9[tp] *= inv * msk[tp];

    // PV: per d-half load 9 V fragments, accumulate tp-inner (order as R11)
    float o[16];
#pragma unroll
    for (int dd = 0; dd < 16; dd++) o[dd] = 0.f;
#pragma unroll
    for (int hh = 0; hh < 2; hh++) {
        ushort8 vfr[9];
#pragma unroll
        for (int tp = 0; tp < 9; tp++)
            vfr[tp] = *reinterpret_cast<const ushort8*>(&Vl[rbase + roff[tp] + hh * 8]);
#pragma unroll
        for (int j = 0; j < 8; j++)
#pragma unroll
            for (int tp = 0; tp < 9; tp++)
                o[hh * 8 + j] += w9[tp] * bf2f(vfr[tp][j]);
    }

    __align__(16) unsigned short ov[16];
#pragma unroll
    for (int dd = 0; dd < 16; dd++) ov[dd] = f2bf(o[dd]);

    // blocked store: tile (b, sblk, kb=h*2+(w>>1)), row=lane, col=(w&1)*16
    unsigned short* dst = aoT + (((size_t)(b * 49 + sblk)) * 16 + (h * 2 + (w >> 1))) * 2048
                        + lane * 32 + (w & 1) * 16;
    *reinterpret_cast<uint4*>(dst)     = *reinterpret_cast<const uint4*>(ov);
    *reinterpret_cast<uint4*>(dst + 8) = *reinterpret_cast<const uint4*>(ov + 8);
}

// ---------------------------------------------------------------------------
// GEMM3 (R11 verbatim): tile 128o x 64s, BK=32, identity uint4 staging,
// 8 MFMA/wave/K-step. grid (49, 3, 4).
// ---------------------------------------------------------------------------
__global__ __launch_bounds__(256) void gemm3(
    const unsigned short* __restrict__ aoT,  // [4][49][16][64][32]
    const unsigned short* __restrict__ wT3,  // [3][16][128][32]
    const float* __restrict__ bias,          // (384)
    float* __restrict__ out)                 // (4,384,3136) f32
{
    __shared__ __align__(16) unsigned short A_lds[128 * 32];
    __shared__ __align__(16) unsigned short B_lds[64 * 32];

    const int sblk = blockIdx.x;             // 0..48
    const int oblk = blockIdx.y;             // 0..2
    const int b  = blockIdx.z;
    const int t  = threadIdx.x;
    const int lane = t & 63, w = t >> 6;
    const int quad = lane >> 4, mrow = lane & 15;
    const int wm = w >> 1, wn = w & 1;       // wave: 64o x 32s quadrant

    const unsigned short* asrc = wT3 + (size_t)oblk * 16 * 4096;
    const unsigned short* bsrc = aoT + ((size_t)(b * 49 + sblk)) * 16 * 2048;

    f32x4_t acc[4][2];
#pragma unroll
    for (int m = 0; m < 4; m++)
#pragma unroll
        for (int n = 0; n < 2; n++) acc[m][n] = (f32x4_t){0.f, 0.f, 0.f, 0.f};

    for (int kb = 0; kb < 16; kb++) {
        const uint4 a0 = *reinterpret_cast<const uint4*>(asrc + (size_t)kb * 4096 + t * 8);
        const uint4 a1 = *reinterpret_cast<const uint4*>(asrc + (size_t)kb * 4096 + 2048 + t * 8);
        const uint4 b0 = *reinterpret_cast<const uint4*>(bsrc + (size_t)kb * 2048 + t * 8);

        __syncthreads();
        *reinterpret_cast<uint4*>(A_lds + t * 8) = a0;
        *reinterpret_cast<uint4*>(A_lds + 2048 + t * 8) = a1;
        *reinterpret_cast<uint4*>(B_lds + t * 8) = b0;
        __syncthreads();

        bf16x8_t af[4], bf[2];
#pragma unroll
        for (int m = 0; m < 4; m++)
            af[m] = *reinterpret_cast<const bf16x8_t*>(&A_lds[(wm * 64 + m * 16 + mrow) * 32 + quad * 8]);
#pragma unroll
        for (int n = 0; n < 2; n++)
            bf[n] = *reinterpret_cast<const bf16x8_t*>(&B_lds[(wn * 32 + n * 16 + mrow) * 32 + quad * 8]);
#pragma unroll
        for (int m = 0; m < 4; m++)
#pragma unroll
            for (int n = 0; n < 2; n++)
                acc[m][n] = __builtin_amdgcn_mfma_f32_16x16x32_bf16(af[m], bf[n], acc[m][n], 0, 0, 0);
    }

    const int o0 = oblk * 128 + wm * 64;
    const int s0 = sblk * 64 + wn * 32;
    float* outb = out + (size_t)b * 384 * HW;
#pragma unroll
    for (int m = 0; m < 4; m++)
#pragma unroll
        for (int n = 0; n < 2; n++) {
            const int ss = s0 + n * 16 + mrow;      // < 3136 always (49*64 exact)
#pragma unroll
            for (int r = 0; r < 4; r++) {
                const int oo = o0 + m * 16 + quad * 4 + r;
                outb[(size_t)oo * HW + ss] = acc[m][n][r] + bias[oo];
            }
        }
}

extern "C" void kernel_launch(void* const* d_in, const int* in_sizes, int n_in,
                              void* d_out, int out_size, void* d_ws, size_t ws_size,
                              hipStream_t stream) {
    const float* x   = (const float*)d_in[0];
    const float* Wq  = (const float*)d_in[1];
    const float* Wkv = (const float*)d_in[2];
    const float* Wo  = (const float*)d_in[3];
    const float* bo  = (const float*)d_in[4];
    float* out = (float*)d_out;

    // ws layout (bf16 elements)
    unsigned short* xT   = (unsigned short*)d_ws;                 // 4*25*12*4096 = 4,915,200
    unsigned short* wT   = xT + (size_t)4915200;                  // 12*12*128*32 =   589,824
    unsigned short* wT3  = wT + (size_t)589824;                   // 3*16*128*32  =   196,608
    unsigned short* qkvT = wT3 + (size_t)196608;                  // 3*4*8*3136*64 = 19,267,584
    unsigned short* aoT  = qkvT + (size_t)(3 * QKV_T);            // 4*49*16*2048 =  6,422,528

    cvt_w<<<dim3(384), 256, 0, stream>>>(Wq, Wkv, Wo, wT, wT3);   // exact: 98304 threads
    cvtT_x<<<dim3(50, 12, 4), 256, 0, stream>>>(x, xT);

    gemm1<<<dim3(25, 12, 4), 256, 0, stream>>>(xT, wT, qkvT);
    natt2<<<dim3(49, 8, 4), 256, 0, stream>>>(qkvT, aoT);
    gemm3<<<dim3(49, 3, 4), 256, 0, stream>>>(aoT, wT3, bo, out);
}

// Round 3
// 144.909 us; speedup vs baseline: 1.0275x; 1.0054x over previous
//
#include <hip/hip_runtime.h>

// ConvAttention2d: B=4, DIM=384, HEADS=8, DH=64, INNER=512, H=W=56, KS=3
// fp32 in/out. Internals: bf16 MFMA GEMMs (fp32 accum), blocked bf16 buffers.
// qkv = x @ [Wq;Wkv] -> 3x3 neighborhood attention -> out = ao @ Wo + bo
// R14: gemm1/gemm3 staging = SINGLE-buffer global_load_lds width=16 (m97/m151
// proven structure: barrier -> issue 4x gload_lds -> barrier(drains vmcnt) ->
// ds_read fragments -> MFMA). Same LDS footprint as R11 (no dbuf, unlike the
// failed R12), removes the uint4->VGPR->ds_write round-trip.
// natt2 / gemm1-epilogue / layouts: R13 verbatim. cvt_w / cvtT_x unchanged.

#define HW 3136
#define WIMG 56
#define QKV_CH 1536
#define SCALE 0.125f
#define KSTR 72            // natt LDS row stride in ushorts (144B, 36 dwords)
#define NROWS 180          // staged rows: s0-59 .. s0+120
#define QKV_T 6422528      // one tensor: 4*8*3136*64 bf16 elems

typedef __bf16 bf16x8_t __attribute__((ext_vector_type(8)));
typedef float f32x4_t __attribute__((ext_vector_type(4)));
typedef unsigned short ushort8 __attribute__((ext_vector_type(8)));

__device__ __forceinline__ float bf2f(unsigned short u) {
    return __uint_as_float(((unsigned int)u) << 16);
}
__device__ __forceinline__ unsigned short f2bf(float f) {
    unsigned int u = __float_as_uint(f);
    u += 0x7FFFu + ((u >> 16) & 1u);   // round-to-nearest-even
    return (unsigned short)(u >> 16);
}

// async global->LDS, 16B per lane. LDS dest = wave-uniform base + lane*16.
__device__ __forceinline__ void gll16(const unsigned short* g, unsigned short* l) {
    __builtin_amdgcn_global_load_lds(
        (const __attribute__((address_space(1))) unsigned int*)g,
        (__attribute__((address_space(3))) unsigned int*)l,
        16, 0, 0);
}

// ---------------------------------------------------------------------------
// Weights f32 -> bf16, both blocked (unchanged):
//   wT  [oblk12][kb12][128o][32k]  for gemm1 (Wq||Wkv, K=384)
//   wT3 [oblk3][kb16][128o][32k]   for gemm3 (Wo, K=512)
// ---------------------------------------------------------------------------
__global__ __launch_bounds__(256) void cvt_w(
    const float* __restrict__ Wq, const float* __restrict__ Wkv,
    const float* __restrict__ Wo,
    unsigned short* __restrict__ wT, unsigned short* __restrict__ wT3)
{
    const int i = blockIdx.x * 256 + threadIdx.x;
    if (i < 73728) {                    // wT: 12*12*128*4 uint4 slots
        const int g = i & 3;
        const int idx3 = i >> 2;        // [oblk][kb][o128]
        const int o128 = idx3 & 127;
        const int rest = idx3 >> 7;     // 0..143
        const int kb = rest % 12, oblk = rest / 12;
        const int o = oblk * 128 + o128;
        const int k0 = kb * 32 + g * 8;
        const float* src = (o < 512) ? (Wq + (size_t)o * 384 + k0)
                                     : (Wkv + (size_t)(o - 512) * 384 + k0);
        const float4 v0 = *reinterpret_cast<const float4*>(src);
        const float4 v1 = *reinterpret_cast<const float4*>(src + 4);
        uint4 u;
        u.x = (unsigned int)f2bf(v0.x) | ((unsigned int)f2bf(v0.y) << 16);
        u.y = (unsigned int)f2bf(v0.z) | ((unsigned int)f2bf(v0.w) << 16);
        u.z = (unsigned int)f2bf(v1.x) | ((unsigned int)f2bf(v1.y) << 16);
        u.w = (unsigned int)f2bf(v1.z) | ((unsigned int)f2bf(v1.w) << 16);
        reinterpret_cast<uint4*>(wT)[i] = u;
    } else {                            // wT3: 3*16*128*4 = 24576 uint4 slots
        const int j = i - 73728;        // [0, 24576)
        const int g = j & 3;
        const int idx3 = j >> 2;        // 0..6143
        const int o128 = idx3 & 127;
        const int rest = idx3 >> 7;     // 0..47
        const int kb = rest % 16, oblk = rest / 16;
        const int o = oblk * 128 + o128;            // < 384
        const float* src = Wo + (size_t)o * 512 + kb * 32 + g * 8;
        const float4 v0 = *reinterpret_cast<const float4*>(src);
        const float4 v1 = *reinterpret_cast<const float4*>(src + 4);
        uint4 u;
        u.x = (unsigned int)f2bf(v0.x) | ((unsigned int)f2bf(v0.y) << 16);
        u.y = (unsigned int)f2bf(v0.z) | ((unsigned int)f2bf(v0.w) << 16);
        u.z = (unsigned int)f2bf(v1.x) | ((unsigned int)f2bf(v1.y) << 16);
        u.w = (unsigned int)f2bf(v1.z) | ((unsigned int)f2bf(v1.w) << 16);
        reinterpret_cast<uint4*>(wT3)[j] = u;
    }
}

// ---------------------------------------------------------------------------
// x (b,c,s) f32 -> blocked bf16 xT[b][sblk25][kb12][128s][32k] (unchanged).
// ---------------------------------------------------------------------------
__global__ __launch_bounds__(256) void cvtT_x(
    const float* __restrict__ x, unsigned short* __restrict__ xT)
{
    __shared__ unsigned short Tl[64 * 36];   // [s][c], pad 36
    const int sblk = blockIdx.x, kblk = blockIdx.y, b = blockIdx.z;
    const int t = threadIdx.x;

    if (sblk == 49) {                   // zero-fill s in [3136,3200)
        unsigned short* dst = xT + (((size_t)b * 25 + 24) * 12 + kblk) * 4096 + 2048;
        *reinterpret_cast<uint4*>(dst + t * 8) = (uint4){0, 0, 0, 0};
        return;
    }

    const float* xp = x + ((size_t)b * 384 + (size_t)kblk * 32) * HW + sblk * 64;
    const int c = t >> 3;                    // 0..31
#pragma unroll
    for (int i = 0; i < 2; i++) {
        const int sc = (t & 7) + 8 * i;      // 0..15 (float4 chunks)
        const float4 v = *reinterpret_cast<const float4*>(xp + (size_t)c * HW + sc * 4);
        const int s4 = sc * 4;
        Tl[(s4 + 0) * 36 + c] = f2bf(v.x);
        Tl[(s4 + 1) * 36 + c] = f2bf(v.y);
        Tl[(s4 + 2) * 36 + c] = f2bf(v.z);
        Tl[(s4 + 3) * 36 + c] = f2bf(v.w);
    }
    __syncthreads();

    const int row = t >> 2, gran = t & 3;
    const uint2 lo = *reinterpret_cast<const uint2*>(&Tl[row * 36 + gran * 8]);
    const uint2 hi = *reinterpret_cast<const uint2*>(&Tl[row * 36 + gran * 8 + 4]);
    uint4 o; o.x = lo.x; o.y = lo.y; o.z = hi.x; o.w = hi.y;
    unsigned short* dst = xT + (((size_t)b * 25 + (sblk >> 1)) * 12 + kblk) * 4096
                        + (sblk & 1) * 2048;
    *reinterpret_cast<uint4*>(dst + t * 8) = o;
}

// ---------------------------------------------------------------------------
// GEMM1 (R14): single-buffer global_load_lds staging, 2 barriers/K-step,
// 16 MFMA/wave. Epilogue writes qkvT[which][b][h][s][64] rows (R13).
// grid (25, 12, 4).
// ---------------------------------------------------------------------------
__global__ __launch_bounds__(256) void gemm1(
    const unsigned short* __restrict__ xT,   // [b][25][12][128][32]
    const unsigned short* __restrict__ wT,   // [12][12][128][32]
    unsigned short* __restrict__ qkvT)       // [3][4][8][3136][64] bf16
{
    __shared__ __align__(16) unsigned short A_lds[128 * 32];
    __shared__ __align__(16) unsigned short B_lds[128 * 32];

    const int sblk = blockIdx.x;             // 0..24
    const int oblk = blockIdx.y;             // 0..11
    const int b  = blockIdx.z;
    const int t  = threadIdx.x;
    const int lane = t & 63, w = t >> 6;
    const int quad = lane >> 4, mrow = lane & 15;
    const int wm = w >> 1, wn = w & 1;       // wave quadrant

    const unsigned short* wsrc = wT + ((size_t)oblk * 12) * 4096;
    const unsigned short* xsrc = xT + (((size_t)b * 25 + sblk) * 12) * 4096;

    f32x4_t acc[4][4];
#pragma unroll
    for (int m = 0; m < 4; m++)
#pragma unroll
        for (int n = 0; n < 4; n++) acc[m][n] = (f32x4_t){0.f, 0.f, 0.f, 0.f};

    for (int kb = 0; kb < 12; kb++) {
        __syncthreads();   // previous iteration's fragment reads complete
        gll16(wsrc + (size_t)kb * 4096 + t * 8,        A_lds + t * 8);
        gll16(wsrc + (size_t)kb * 4096 + 2048 + t * 8, A_lds + 2048 + t * 8);
        gll16(xsrc + (size_t)kb * 4096 + t * 8,        B_lds + t * 8);
        gll16(xsrc + (size_t)kb * 4096 + 2048 + t * 8, B_lds + 2048 + t * 8);
        __syncthreads();   // drains vmcnt(0): LDS tile ready

        bf16x8_t af[4], bf[4];
#pragma unroll
        for (int m = 0; m < 4; m++)
            af[m] = *reinterpret_cast<const bf16x8_t*>(&A_lds[(wm * 64 + m * 16 + mrow) * 32 + quad * 8]);
#pragma unroll
        for (int n = 0; n < 4; n++)
            bf[n] = *reinterpret_cast<const bf16x8_t*>(&B_lds[(wn * 64 + n * 16 + mrow) * 32 + quad * 8]);
#pragma unroll
        for (int m = 0; m < 4; m++)
#pragma unroll
            for (int n = 0; n < 4; n++)
                acc[m][n] = __builtin_amdgcn_mfma_f32_16x16x32_bf16(af[m], bf[n], acc[m][n], 0, 0, 0);
    }

    // epilogue: oo = oblk*128 + wm*64 + m*16 + quad*4 + r
    //   which = oblk>>2 (0=q,1=k,2=v), head = (oblk&3)*2 + wm, d = m*16+quad*4+r
    const int which = oblk >> 2;
    const int hq = (oblk & 3) * 2 + wm;
    const int s0 = sblk * 128 + wn * 64;
    unsigned short* outb = qkvT + (size_t)which * QKV_T
                         + ((size_t)(b * 8 + hq) * HW) * 64;
#pragma unroll
    for (int m = 0; m < 4; m++) {
        const int d0 = m * 16 + quad * 4;
#pragma unroll
        for (int n = 0; n < 4; n++) {
            const int ss = s0 + n * 16 + mrow;
            if (ss < HW) {
                uint2 u;
                u.x = (unsigned int)f2bf(acc[m][n][0]) | ((unsigned int)f2bf(acc[m][n][1]) << 16);
                u.y = (unsigned int)f2bf(acc[m][n][2]) | ((unsigned int)f2bf(acc[m][n][3]) << 16);
                *reinterpret_cast<uint2*>(outb + (size_t)ss * 64 + d0) = u;
            }
        }
    }
}

// ---------------------------------------------------------------------------
// Neighborhood attention (R13 verbatim): [s][d] LDS tiles, b128 reads.
// ---------------------------------------------------------------------------
__global__ __launch_bounds__(256) void natt2(
    const unsigned short* __restrict__ qkvT, // [3][4][8][3136][64] bf16
    unsigned short* __restrict__ aoT)        // [4][49][16][64][32] bf16
{
    __shared__ __align__(16) unsigned short smem[2 * NROWS * KSTR]; // Kl | Vl
    unsigned short* Kl = smem;
    unsigned short* Vl = smem + NROWS * KSTR;
    float* dred = reinterpret_cast<float*>(smem);  // overlays Kl after dots

    const int t = threadIdx.x, lane = t & 63, w = t >> 6;
    const int sblk = blockIdx.x;
    const int s0 = sblk * 64;
    const int s  = s0 + lane;
    const int h  = blockIdx.y, b = blockIdx.z;
    const int y  = s / WIMG, xx = s % WIMG;

    const unsigned short* qg = qkvT + ((size_t)(b * 8 + h) * HW) * 64;
    const unsigned short* kg = qg + (size_t)QKV_T;
    const unsigned short* vg = qg + (size_t)(2 * QKV_T);

    // stage K/V rows [s0-59, s0+120] -> 180 rows x 64 d (1440 16B chunks)
#pragma unroll
    for (int i = 0; i < 6; i++) {
        const int f = i * 256 + t;        // 0..1535, use < 1440
        if (f < NROWS * 8) {
            const int row = f >> 3, c8 = f & 7;
            int srow = s0 - 59 + row;
            srow = min(max(srow, 0), HW - 1);
            const uint4 k4 = *reinterpret_cast<const uint4*>(kg + (size_t)srow * 64 + c8 * 8);
            const uint4 v4 = *reinterpret_cast<const uint4*>(vg + (size_t)srow * 64 + c8 * 8);
            *reinterpret_cast<uint4*>(&Kl[row * KSTR + c8 * 8]) = k4;
            *reinterpret_cast<uint4*>(&Vl[row * KSTR + c8 * 8]) = v4;
        }
    }

    int   roff[9];
    float msk[9];
#pragma unroll
    for (int ty = 0; ty < 3; ty++)
#pragma unroll
        for (int tx = 0; tx < 3; tx++) {
            const int tap = ty * 3 + tx;
            const int ny = y + ty - 1, nx = xx + tx - 1;
            const bool v = (ny >= 0) && (ny < WIMG) && (nx >= 0) && (nx < WIMG);
            roff[tap] = (v ? ((ty - 1) * WIMG + (tx - 1)) : 0) * KSTR;
            msk[tap]  = v ? 1.f : 0.f;
        }

    // q: 16 channels for this (pos, w) — vectorized global
    float qv[16];
    {
        const uint4 q0 = *reinterpret_cast<const uint4*>(qg + (size_t)s * 64 + w * 16);
        const uint4 q1 = *reinterpret_cast<const uint4*>(qg + (size_t)s * 64 + w * 16 + 8);
        qv[0] = bf2f((unsigned short)(q0.x & 0xffff)); qv[1] = bf2f((unsigned short)(q0.x >> 16));
        qv[2] = bf2f((unsigned short)(q0.y & 0xffff)); qv[3] = bf2f((unsigned short)(q0.y >> 16));
        qv[4] = bf2f((unsigned short)(q0.z & 0xffff)); qv[5] = bf2f((unsigned short)(q0.z >> 16));
        qv[6] = bf2f((unsigned short)(q0.w & 0xffff)); qv[7] = bf2f((unsigned short)(q0.w >> 16));
        qv[8]  = bf2f((unsigned short)(q1.x & 0xffff)); qv[9]  = bf2f((unsigned short)(q1.x >> 16));
        qv[10] = bf2f((unsigned short)(q1.y & 0xffff)); qv[11] = bf2f((unsigned short)(q1.y >> 16));
        qv[12] = bf2f((unsigned short)(q1.z & 0xffff)); qv[13] = bf2f((unsigned short)(q1.z >> 16));
        qv[14] = bf2f((unsigned short)(q1.w & 0xffff)); qv[15] = bf2f((unsigned short)(q1.w >> 16));
    }

    __syncthreads();

    const int rbase = (59 + lane) * KSTR + w * 16;   // own row, own d-range

    float dots[9];
#pragma unroll
    for (int tp = 0; tp < 9; tp++) dots[tp] = 0.f;
#pragma unroll
    for (int hh = 0; hh < 2; hh++) {
#pragma unroll
        for (int tp = 0; tp < 9; tp++) {
            const ushort8 kk = *reinterpret_cast<const ushort8*>(&Kl[rbase + roff[tp] + hh * 8]);
#pragma unroll
            for (int j = 0; j < 8; j++)
                dots[tp] += qv[hh * 8 + j] * bf2f(kk[j]);   // dd ascending per tap
        }
    }

    __syncthreads();
#pragma unroll
    for (int tp = 0; tp < 9; tp++) dred[(tp * 4 + w) * 64 + lane] = dots[tp];
    __syncthreads();

    float mx = -1e30f, dt[9];
#pragma unroll
    for (int tp = 0; tp < 9; tp++) {
        const float sum = dred[(tp * 4 + 0) * 64 + lane] + dred[(tp * 4 + 1) * 64 + lane] +
                          dred[(tp * 4 + 2) * 64 + lane] + dred[(tp * 4 + 3) * 64 + lane];
        dt[tp] = msk[tp] * (sum * SCALE);
        mx = fmaxf(mx, dt[tp]);
    }
    float se = 0.f, w9[9];
#pragma unroll
    for (int tp = 0; tp < 9; tp++) { w9[tp] = __expf(dt[tp] - mx); se += w9[tp]; }
    const float inv = 1.f / se;
#pragma unroll
    for (int tp = 0; tp < 9; tp++) w9[tp] *= inv * msk[tp];

    // PV: per d-half load 9 V fragments, accumulate tp-inner (order as R11)
    float o[16];
#pragma unroll
    for (int dd = 0; dd < 16; dd++) o[dd] = 0.f;
#pragma unroll
    for (int hh = 0; hh < 2; hh++) {
        ushort8 vfr[9];
#pragma unroll
        for (int tp = 0; tp < 9; tp++)
            vfr[tp] = *reinterpret_cast<const ushort8*>(&Vl[rbase + roff[tp] + hh * 8]);
#pragma unroll
        for (int j = 0; j < 8; j++)
#pragma unroll
            for (int tp = 0; tp < 9; tp++)
                o[hh * 8 + j] += w9[tp] * bf2f(vfr[tp][j]);
    }

    __align__(16) unsigned short ov[16];
#pragma unroll
    for (int dd = 0; dd < 16; dd++) ov[dd] = f2bf(o[dd]);

    // blocked store: tile (b, sblk, kb=h*2+(w>>1)), row=lane, col=(w&1)*16
    unsigned short* dst = aoT + (((size_t)(b * 49 + sblk)) * 16 + (h * 2 + (w >> 1))) * 2048
                        + lane * 32 + (w & 1) * 16;
    *reinterpret_cast<uint4*>(dst)     = *reinterpret_cast<const uint4*>(ov);
    *reinterpret_cast<uint4*>(dst + 8) = *reinterpret_cast<const uint4*>(ov + 8);
}

// ---------------------------------------------------------------------------
// GEMM3 (R14): single-buffer global_load_lds staging, 2 barriers/K-step,
// 8 MFMA/wave. grid (49, 3, 4).
// ---------------------------------------------------------------------------
__global__ __launch_bounds__(256) void gemm3(
    const unsigned short* __restrict__ aoT,  // [4][49][16][64][32]
    const unsigned short* __restrict__ wT3,  // [3][16][128][32]
    const float* __restrict__ bias,          // (384)
    float* __restrict__ out)                 // (4,384,3136) f32
{
    __shared__ __align__(16) unsigned short A_lds[128 * 32];
    __shared__ __align__(16) unsigned short B_lds[64 * 32];

    const int sblk = blockIdx.x;             // 0..48
    const int oblk = blockIdx.y;             // 0..2
    const int b  = blockIdx.z;
    const int t  = threadIdx.x;
    const int lane = t & 63, w = t >> 6;
    const int quad = lane >> 4, mrow = lane & 15;
    const int wm = w >> 1, wn = w & 1;       // wave: 64o x 32s quadrant

    const unsigned short* asrc = wT3 + (size_t)oblk * 16 * 4096;
    const unsigned short* bsrc = aoT + ((size_t)(b * 49 + sblk)) * 16 * 2048;

    f32x4_t acc[4][2];
#pragma unroll
    for (int m = 0; m < 4; m++)
#pragma unroll
        for (int n = 0; n < 2; n++) acc[m][n] = (f32x4_t){0.f, 0.f, 0.f, 0.f};

    for (int kb = 0; kb < 16; kb++) {
        __syncthreads();
        gll16(asrc + (size_t)kb * 4096 + t * 8,        A_lds + t * 8);
        gll16(asrc + (size_t)kb * 4096 + 2048 + t * 8, A_lds + 2048 + t * 8);
        gll16(bsrc + (size_t)kb * 2048 + t * 8,        B_lds + t * 8);
        __syncthreads();

        bf16x8_t af[4], bf[2];
#pragma unroll
        for (int m = 0; m < 4; m++)
            af[m] = *reinterpret_cast<const bf16x8_t*>(&A_lds[(wm * 64 + m * 16 + mrow) * 32 + quad * 8]);
#pragma unroll
        for (int n = 0; n < 2; n++)
            bf[n] = *reinterpret_cast<const bf16x8_t*>(&B_lds[(wn * 32 + n * 16 + mrow) * 32 + quad * 8]);
#pragma unroll
        for (int m = 0; m < 4; m++)
#pragma unroll
            for (int n = 0; n < 2; n++)
                acc[m][n] = __builtin_amdgcn_mfma_f32_16x16x32_bf16(af[m], bf[n], acc[m][n], 0, 0, 0);
    }

    const int o0 = oblk * 128 + wm * 64;
    const int s0 = sblk * 64 + wn * 32;
    float* outb = out + (size_t)b * 384 * HW;
#pragma unroll
    for (int m = 0; m < 4; m++)
#pragma unroll
        for (int n = 0; n < 2; n++) {
            const int ss = s0 + n * 16 + mrow;      // < 3136 always (49*64 exact)
#pragma unroll
            for (int r = 0; r < 4; r++) {
                const int oo = o0 + m * 16 + quad * 4 + r;
                outb[(size_t)oo * HW + ss] = acc[m][n][r] + bias[oo];
            }
        }
}

extern "C" void kernel_launch(void* const* d_in, const int* in_sizes, int n_in,
                              void* d_out, int out_size, void* d_ws, size_t ws_size,
                              hipStream_t stream) {
    const float* x   = (const float*)d_in[0];
    const float* Wq  = (const float*)d_in[1];
    const float* Wkv = (const float*)d_in[2];
    const float* Wo  = (const float*)d_in[3];
    const float* bo  = (const float*)d_in[4];
    float* out = (float*)d_out;

    // ws layout (bf16 elements)
    unsigned short* xT   = (unsigned short*)d_ws;                 // 4*25*12*4096 = 4,915,200
    unsigned short* wT   = xT + (size_t)4915200;                  // 12*12*128*32 =   589,824
    unsigned short* wT3  = wT + (size_t)589824;                   // 3*16*128*32  =   196,608
    unsigned short* qkvT = wT3 + (size_t)196608;                  // 3*4*8*3136*64 = 19,267,584
    unsigned short* aoT  = qkvT + (size_t)(3 * QKV_T);            // 4*49*16*2048 =  6,422,528

    cvt_w<<<dim3(384), 256, 0, stream>>>(Wq, Wkv, Wo, wT, wT3);   // exact: 98304 threads
    cvtT_x<<<dim3(50, 12, 4), 256, 0, stream>>>(x, xT);

    gemm1<<<dim3(25, 12, 4), 256, 0, stream>>>(xT, wT, qkvT);
    natt2<<<dim3(49, 8, 4), 256, 0, stream>>>(qkvT, aoT);
    gemm3<<<dim3(49, 3, 4), 256, 0, stream>>>(aoT, wT3, bo, out);
}

// Round 4
// 143.099 us; speedup vs baseline: 1.0405x; 1.0126x over previous
//
#include <hip/hip_runtime.h>

// ConvAttention2d: B=4, DIM=384, HEADS=8, DH=64, INNER=512, H=W=56, KS=3
// fp32 in/out. Internals: bf16 MFMA GEMMs (fp32 accum), blocked bf16 buffers.
// qkv = x @ [Wq;Wkv] -> 3x3 neighborhood attention -> out = ao @ Wo + bo
// R15: kernel-count 5 -> 4. cvt_w and cvtT_x (independent) merged into one
// dispatch cvt_all (grid concatenation; bodies unchanged). Tests whether
// per-launch overhead is a large share of the measured window.
// gemm1/natt2/gemm3: R14 verbatim (single-buffer global_load_lds GEMMs).

#define HW 3136
#define WIMG 56
#define QKV_CH 1536
#define SCALE 0.125f
#define KSTR 72            // natt LDS row stride in ushorts (144B, 36 dwords)
#define NROWS 180          // staged rows: s0-59 .. s0+120
#define QKV_T 6422528      // one tensor: 4*8*3136*64 bf16 elems

typedef __bf16 bf16x8_t __attribute__((ext_vector_type(8)));
typedef float f32x4_t __attribute__((ext_vector_type(4)));
typedef unsigned short ushort8 __attribute__((ext_vector_type(8)));

__device__ __forceinline__ float bf2f(unsigned short u) {
    return __uint_as_float(((unsigned int)u) << 16);
}
__device__ __forceinline__ unsigned short f2bf(float f) {
    unsigned int u = __float_as_uint(f);
    u += 0x7FFFu + ((u >> 16) & 1u);   // round-to-nearest-even
    return (unsigned short)(u >> 16);
}

// async global->LDS, 16B per lane. LDS dest = wave-uniform base + lane*16.
__device__ __forceinline__ void gll16(const unsigned short* g, unsigned short* l) {
    __builtin_amdgcn_global_load_lds(
        (const __attribute__((address_space(1))) unsigned int*)g,
        (__attribute__((address_space(3))) unsigned int*)l,
        16, 0, 0);
}

// ---------------------------------------------------------------------------
// cvt_all (R15): merged preprocessing.
//   blocks [0, 2400):    cvtT_x body — x (b,c,s) f32 -> blocked bf16
//                        xT[b][sblk25][kb12][128s][32k], tail zero-filled.
//   blocks [2400, 2784): cvt_w body — weights f32 -> bf16 blocked:
//                        wT [oblk12][kb12][128o][32k], wT3 [oblk3][kb16][128o][32k]
// Bodies are verbatim from R14's cvt_w / cvtT_x.
// ---------------------------------------------------------------------------
__global__ __launch_bounds__(256) void cvt_all(
    const float* __restrict__ x,
    const float* __restrict__ Wq, const float* __restrict__ Wkv,
    const float* __restrict__ Wo,
    unsigned short* __restrict__ xT,
    unsigned short* __restrict__ wT, unsigned short* __restrict__ wT3)
{
    __shared__ unsigned short Tl[64 * 36];   // [s][c], pad 36 (cvtT_x branch only)
    const int bx = blockIdx.x;
    const int t = threadIdx.x;

    if (bx < 2400) {
        // ------- cvtT_x body -------
        const int sblk = bx % 50;
        const int kblk = (bx / 50) % 12;
        const int b    = bx / 600;

        if (sblk == 49) {               // zero-fill s in [3136,3200)
            unsigned short* dst = xT + (((size_t)b * 25 + 24) * 12 + kblk) * 4096 + 2048;
            *reinterpret_cast<uint4*>(dst + t * 8) = (uint4){0, 0, 0, 0};
            return;
        }

        const float* xp = x + ((size_t)b * 384 + (size_t)kblk * 32) * HW + sblk * 64;
        const int c = t >> 3;                    // 0..31
#pragma unroll
        for (int i = 0; i < 2; i++) {
            const int sc = (t & 7) + 8 * i;      // 0..15 (float4 chunks)
            const float4 v = *reinterpret_cast<const float4*>(xp + (size_t)c * HW + sc * 4);
            const int s4 = sc * 4;
            Tl[(s4 + 0) * 36 + c] = f2bf(v.x);
            Tl[(s4 + 1) * 36 + c] = f2bf(v.y);
            Tl[(s4 + 2) * 36 + c] = f2bf(v.z);
            Tl[(s4 + 3) * 36 + c] = f2bf(v.w);
        }
        __syncthreads();

        const int row = t >> 2, gran = t & 3;
        const uint2 lo = *reinterpret_cast<const uint2*>(&Tl[row * 36 + gran * 8]);
        const uint2 hi = *reinterpret_cast<const uint2*>(&Tl[row * 36 + gran * 8 + 4]);
        uint4 o; o.x = lo.x; o.y = lo.y; o.z = hi.x; o.w = hi.y;
        unsigned short* dst = xT + (((size_t)b * 25 + (sblk >> 1)) * 12 + kblk) * 4096
                            + (sblk & 1) * 2048;
        *reinterpret_cast<uint4*>(dst + t * 8) = o;
        return;
    }

    // ------- cvt_w body -------
    const int i = (bx - 2400) * 256 + t;
    if (i < 73728) {                    // wT: 12*12*128*4 uint4 slots
        const int g = i & 3;
        const int idx3 = i >> 2;        // [oblk][kb][o128]
        const int o128 = idx3 & 127;
        const int rest = idx3 >> 7;     // 0..143
        const int kb = rest % 12, oblk = rest / 12;
        const int o = oblk * 128 + o128;
        const int k0 = kb * 32 + g * 8;
        const float* src = (o < 512) ? (Wq + (size_t)o * 384 + k0)
                                     : (Wkv + (size_t)(o - 512) * 384 + k0);
        const float4 v0 = *reinterpret_cast<const float4*>(src);
        const float4 v1 = *reinterpret_cast<const float4*>(src + 4);
        uint4 u;
        u.x = (unsigned int)f2bf(v0.x) | ((unsigned int)f2bf(v0.y) << 16);
        u.y = (unsigned int)f2bf(v0.z) | ((unsigned int)f2bf(v0.w) << 16);
        u.z = (unsigned int)f2bf(v1.x) | ((unsigned int)f2bf(v1.y) << 16);
        u.w = (unsigned int)f2bf(v1.z) | ((unsigned int)f2bf(v1.w) << 16);
        reinterpret_cast<uint4*>(wT)[i] = u;
    } else {                            // wT3: 3*16*128*4 = 24576 uint4 slots
        const int j = i - 73728;        // [0, 24576)
        const int g = j & 3;
        const int idx3 = j >> 2;        // 0..6143
        const int o128 = idx3 & 127;
        const int rest = idx3 >> 7;     // 0..47
        const int kb = rest % 16, oblk = rest / 16;
        const int o = oblk * 128 + o128;            // < 384
        const float* src = Wo + (size_t)o * 512 + kb * 32 + g * 8;
        const float4 v0 = *reinterpret_cast<const float4*>(src);
        const float4 v1 = *reinterpret_cast<const float4*>(src + 4);
        uint4 u;
        u.x = (unsigned int)f2bf(v0.x) | ((unsigned int)f2bf(v0.y) << 16);
        u.y = (unsigned int)f2bf(v0.z) | ((unsigned int)f2bf(v0.w) << 16);
        u.z = (unsigned int)f2bf(v1.x) | ((unsigned int)f2bf(v1.y) << 16);
        u.w = (unsigned int)f2bf(v1.z) | ((unsigned int)f2bf(v1.w) << 16);
        reinterpret_cast<uint4*>(wT3)[j] = u;
    }
}

// ---------------------------------------------------------------------------
// GEMM1 (R14 verbatim): single-buffer global_load_lds staging, 2 barriers/
// K-step, 16 MFMA/wave. Epilogue writes qkvT[which][b][h][s][64] rows.
// grid (25, 12, 4).
// ---------------------------------------------------------------------------
__global__ __launch_bounds__(256) void gemm1(
    const unsigned short* __restrict__ xT,   // [b][25][12][128][32]
    const unsigned short* __restrict__ wT,   // [12][12][128][32]
    unsigned short* __restrict__ qkvT)       // [3][4][8][3136][64] bf16
{
    __shared__ __align__(16) unsigned short A_lds[128 * 32];
    __shared__ __align__(16) unsigned short B_lds[128 * 32];

    const int sblk = blockIdx.x;             // 0..24
    const int oblk = blockIdx.y;             // 0..11
    const int b  = blockIdx.z;
    const int t  = threadIdx.x;
    const int lane = t & 63, w = t >> 6;
    const int quad = lane >> 4, mrow = lane & 15;
    const int wm = w >> 1, wn = w & 1;       // wave quadrant

    const unsigned short* wsrc = wT + ((size_t)oblk * 12) * 4096;
    const unsigned short* xsrc = xT + (((size_t)b * 25 + sblk) * 12) * 4096;

    f32x4_t acc[4][4];
#pragma unroll
    for (int m = 0; m < 4; m++)
#pragma unroll
        for (int n = 0; n < 4; n++) acc[m][n] = (f32x4_t){0.f, 0.f, 0.f, 0.f};

    for (int kb = 0; kb < 12; kb++) {
        __syncthreads();   // previous iteration's fragment reads complete
        gll16(wsrc + (size_t)kb * 4096 + t * 8,        A_lds + t * 8);
        gll16(wsrc + (size_t)kb * 4096 + 2048 + t * 8, A_lds + 2048 + t * 8);
        gll16(xsrc + (size_t)kb * 4096 + t * 8,        B_lds + t * 8);
        gll16(xsrc + (size_t)kb * 4096 + 2048 + t * 8, B_lds + 2048 + t * 8);
        __syncthreads();   // drains vmcnt(0): LDS tile ready

        bf16x8_t af[4], bf[4];
#pragma unroll
        for (int m = 0; m < 4; m++)
            af[m] = *reinterpret_cast<const bf16x8_t*>(&A_lds[(wm * 64 + m * 16 + mrow) * 32 + quad * 8]);
#pragma unroll
        for (int n = 0; n < 4; n++)
            bf[n] = *reinterpret_cast<const bf16x8_t*>(&B_lds[(wn * 64 + n * 16 + mrow) * 32 + quad * 8]);
#pragma unroll
        for (int m = 0; m < 4; m++)
#pragma unroll
            for (int n = 0; n < 4; n++)
                acc[m][n] = __builtin_amdgcn_mfma_f32_16x16x32_bf16(af[m], bf[n], acc[m][n], 0, 0, 0);
    }

    // epilogue: oo = oblk*128 + wm*64 + m*16 + quad*4 + r
    //   which = oblk>>2 (0=q,1=k,2=v), head = (oblk&3)*2 + wm, d = m*16+quad*4+r
    const int which = oblk >> 2;
    const int hq = (oblk & 3) * 2 + wm;
    const int s0 = sblk * 128 + wn * 64;
    unsigned short* outb = qkvT + (size_t)which * QKV_T
                         + ((size_t)(b * 8 + hq) * HW) * 64;
#pragma unroll
    for (int m = 0; m < 4; m++) {
        const int d0 = m * 16 + quad * 4;
#pragma unroll
        for (int n = 0; n < 4; n++) {
            const int ss = s0 + n * 16 + mrow;
            if (ss < HW) {
                uint2 u;
                u.x = (unsigned int)f2bf(acc[m][n][0]) | ((unsigned int)f2bf(acc[m][n][1]) << 16);
                u.y = (unsigned int)f2bf(acc[m][n][2]) | ((unsigned int)f2bf(acc[m][n][3]) << 16);
                *reinterpret_cast<uint2*>(outb + (size_t)ss * 64 + d0) = u;
            }
        }
    }
}

// ---------------------------------------------------------------------------
// Neighborhood attention (R13/R14 verbatim): [s][d] LDS tiles, b128 reads.
// ---------------------------------------------------------------------------
__global__ __launch_bounds__(256) void natt2(
    const unsigned short* __restrict__ qkvT, // [3][4][8][3136][64] bf16
    unsigned short* __restrict__ aoT)        // [4][49][16][64][32] bf16
{
    __shared__ __align__(16) unsigned short smem[2 * NROWS * KSTR]; // Kl | Vl
    unsigned short* Kl = smem;
    unsigned short* Vl = smem + NROWS * KSTR;
    float* dred = reinterpret_cast<float*>(smem);  // overlays Kl after dots

    const int t = threadIdx.x, lane = t & 63, w = t >> 6;
    const int sblk = blockIdx.x;
    const int s0 = sblk * 64;
    const int s  = s0 + lane;
    const int h  = blockIdx.y, b = blockIdx.z;
    const int y  = s / WIMG, xx = s % WIMG;

    const unsigned short* qg = qkvT + ((size_t)(b * 8 + h) * HW) * 64;
    const unsigned short* kg = qg + (size_t)QKV_T;
    const unsigned short* vg = qg + (size_t)(2 * QKV_T);

    // stage K/V rows [s0-59, s0+120] -> 180 rows x 64 d (1440 16B chunks)
#pragma unroll
    for (int i = 0; i < 6; i++) {
        const int f = i * 256 + t;        // 0..1535, use < 1440
        if (f < NROWS * 8) {
            const int row = f >> 3, c8 = f & 7;
            int srow = s0 - 59 + row;
            srow = min(max(srow, 0), HW - 1);
            const uint4 k4 = *reinterpret_cast<const uint4*>(kg + (size_t)srow * 64 + c8 * 8);
            const uint4 v4 = *reinterpret_cast<const uint4*>(vg + (size_t)srow * 64 + c8 * 8);
            *reinterpret_cast<uint4*>(&Kl[row * KSTR + c8 * 8]) = k4;
            *reinterpret_cast<uint4*>(&Vl[row * KSTR + c8 * 8]) = v4;
        }
    }

    int   roff[9];
    float msk[9];
#pragma unroll
    for (int ty = 0; ty < 3; ty++)
#pragma unroll
        for (int tx = 0; tx < 3; tx++) {
            const int tap = ty * 3 + tx;
            const int ny = y + ty - 1, nx = xx + tx - 1;
            const bool v = (ny >= 0) && (ny < WIMG) && (nx >= 0) && (nx < WIMG);
            roff[tap] = (v ? ((ty - 1) * WIMG + (tx - 1)) : 0) * KSTR;
            msk[tap]  = v ? 1.f : 0.f;
        }

    // q: 16 channels for this (pos, w) — vectorized global
    float qv[16];
    {
        const uint4 q0 = *reinterpret_cast<const uint4*>(qg + (size_t)s * 64 + w * 16);
        const uint4 q1 = *reinterpret_cast<const uint4*>(qg + (size_t)s * 64 + w * 16 + 8);
        qv[0] = bf2f((unsigned short)(q0.x & 0xffff)); qv[1] = bf2f((unsigned short)(q0.x >> 16));
        qv[2] = bf2f((unsigned short)(q0.y & 0xffff)); qv[3] = bf2f((unsigned short)(q0.y >> 16));
        qv[4] = bf2f((unsigned short)(q0.z & 0xffff)); qv[5] = bf2f((unsigned short)(q0.z >> 16));
        qv[6] = bf2f((unsigned short)(q0.w & 0xffff)); qv[7] = bf2f((unsigned short)(q0.w >> 16));
        qv[8]  = bf2f((unsigned short)(q1.x & 0xffff)); qv[9]  = bf2f((unsigned short)(q1.x >> 16));
        qv[10] = bf2f((unsigned short)(q1.y & 0xffff)); qv[11] = bf2f((unsigned short)(q1.y >> 16));
        qv[12] = bf2f((unsigned short)(q1.z & 0xffff)); qv[13] = bf2f((unsigned short)(q1.z >> 16));
        qv[14] = bf2f((unsigned short)(q1.w & 0xffff)); qv[15] = bf2f((unsigned short)(q1.w >> 16));
    }

    __syncthreads();

    const int rbase = (59 + lane) * KSTR + w * 16;   // own row, own d-range

    float dots[9];
#pragma unroll
    for (int tp = 0; tp < 9; tp++) dots[tp] = 0.f;
#pragma unroll
    for (int hh = 0; hh < 2; hh++) {
#pragma unroll
        for (int tp = 0; tp < 9; tp++) {
            const ushort8 kk = *reinterpret_cast<const ushort8*>(&Kl[rbase + roff[tp] + hh * 8]);
#pragma unroll
            for (int j = 0; j < 8; j++)
                dots[tp] += qv[hh * 8 + j] * bf2f(kk[j]);   // dd ascending per tap
        }
    }

    __syncthreads();
#pragma unroll
    for (int tp = 0; tp < 9; tp++) dred[(tp * 4 + w) * 64 + lane] = dots[tp];
    __syncthreads();

    float mx = -1e30f, dt[9];
#pragma unroll
    for (int tp = 0; tp < 9; tp++) {
        const float sum = dred[(tp * 4 + 0) * 64 + lane] + dred[(tp * 4 + 1) * 64 + lane] +
                          dred[(tp * 4 + 2) * 64 + lane] + dred[(tp * 4 + 3) * 64 + lane];
        dt[tp] = msk[tp] * (sum * SCALE);
        mx = fmaxf(mx, dt[tp]);
    }
    float se = 0.f, w9[9];
#pragma unroll
    for (int tp = 0; tp < 9; tp++) { w9[tp] = __expf(dt[tp] - mx); se += w9[tp]; }
    const float inv = 1.f / se;
#pragma unroll
    for (int tp = 0; tp < 9; tp++) w9[tp] *= inv * msk[tp];

    // PV: per d-half load 9 V fragments, accumulate tp-inner (order as R11)
    float o[16];
#pragma unroll
    for (int dd = 0; dd < 16; dd++) o[dd] = 0.f;
#pragma unroll
    for (int hh = 0; hh < 2; hh++) {
        ushort8 vfr[9];
#pragma unroll
        for (int tp = 0; tp < 9; tp++)
            vfr[tp] = *reinterpret_cast<const ushort8*>(&Vl[rbase + roff[tp] + hh * 8]);
#pragma unroll
        for (int j = 0; j < 8; j++)
#pragma unroll
            for (int tp = 0; tp < 9; tp++)
                o[hh * 8 + j] += w9[tp] * bf2f(vfr[tp][j]);
    }

    __align__(16) unsigned short ov[16];
#pragma unroll
    for (int dd = 0; dd < 16; dd++) ov[dd] = f2bf(o[dd]);

    // blocked store: tile (b, sblk, kb=h*2+(w>>1)), row=lane, col=(w&1)*16
    unsigned short* dst = aoT + (((size_t)(b * 49 + sblk)) * 16 + (h * 2 + (w >> 1))) * 2048
                        + lane * 32 + (w & 1) * 16;
    *reinterpret_cast<uint4*>(dst)     = *reinterpret_cast<const uint4*>(ov);
    *reinterpret_cast<uint4*>(dst + 8) = *reinterpret_cast<const uint4*>(ov + 8);
}

// ---------------------------------------------------------------------------
// GEMM3 (R14 verbatim): single-buffer global_load_lds staging, 2 barriers/
// K-step, 8 MFMA/wave. grid (49, 3, 4).
// ---------------------------------------------------------------------------
__global__ __launch_bounds__(256) void gemm3(
    const unsigned short* __restrict__ aoT,  // [4][49][16][64][32]
    const unsigned short* __restrict__ wT3,  // [3][16][128][32]
    const float* __restrict__ bias,          // (384)
    float* __restrict__ out)                 // (4,384,3136) f32
{
    __shared__ __align__(16) unsigned short A_lds[128 * 32];
    __shared__ __align__(16) unsigned short B_lds[64 * 32];

    const int sblk = blockIdx.x;             // 0..48
    const int oblk = blockIdx.y;             // 0..2
    const int b  = blockIdx.z;
    const int t  = threadIdx.x;
    const int lane = t & 63, w = t >> 6;
    const int quad = lane >> 4, mrow = lane & 15;
    const int wm = w >> 1, wn = w & 1;       // wave: 64o x 32s quadrant

    const unsigned short* asrc = wT3 + (size_t)oblk * 16 * 4096;
    const unsigned short* bsrc = aoT + ((size_t)(b * 49 + sblk)) * 16 * 2048;

    f32x4_t acc[4][2];
#pragma unroll
    for (int m = 0; m < 4; m++)
#pragma unroll
        for (int n = 0; n < 2; n++) acc[m][n] = (f32x4_t){0.f, 0.f, 0.f, 0.f};

    for (int kb = 0; kb < 16; kb++) {
        __syncthreads();
        gll16(asrc + (size_t)kb * 4096 + t * 8,        A_lds + t * 8);
        gll16(asrc + (size_t)kb * 4096 + 2048 + t * 8, A_lds + 2048 + t * 8);
        gll16(bsrc + (size_t)kb * 2048 + t * 8,        B_lds + t * 8);
        __syncthreads();

        bf16x8_t af[4], bf[2];
#pragma unroll
        for (int m = 0; m < 4; m++)
            af[m] = *reinterpret_cast<const bf16x8_t*>(&A_lds[(wm * 64 + m * 16 + mrow) * 32 + quad * 8]);
#pragma unroll
        for (int n = 0; n < 2; n++)
            bf[n] = *reinterpret_cast<const bf16x8_t*>(&B_lds[(wn * 32 + n * 16 + mrow) * 32 + quad * 8]);
#pragma unroll
        for (int m = 0; m < 4; m++)
#pragma unroll
            for (int n = 0; n < 2; n++)
                acc[m][n] = __builtin_amdgcn_mfma_f32_16x16x32_bf16(af[m], bf[n], acc[m][n], 0, 0, 0);
    }

    const int o0 = oblk * 128 + wm * 64;
    const int s0 = sblk * 64 + wn * 32;
    float* outb = out + (size_t)b * 384 * HW;
#pragma unroll
    for (int m = 0; m < 4; m++)
#pragma unroll
        for (int n = 0; n < 2; n++) {
            const int ss = s0 + n * 16 + mrow;      // < 3136 always (49*64 exact)
#pragma unroll
            for (int r = 0; r < 4; r++) {
                const int oo = o0 + m * 16 + quad * 4 + r;
                outb[(size_t)oo * HW + ss] = acc[m][n][r] + bias[oo];
            }
        }
}

extern "C" void kernel_launch(void* const* d_in, const int* in_sizes, int n_in,
                              void* d_out, int out_size, void* d_ws, size_t ws_size,
                              hipStream_t stream) {
    const float* x   = (const float*)d_in[0];
    const float* Wq  = (const float*)d_in[1];
    const float* Wkv = (const float*)d_in[2];
    const float* Wo  = (const float*)d_in[3];
    const float* bo  = (const float*)d_in[4];
    float* out = (float*)d_out;

    // ws layout (bf16 elements)
    unsigned short* xT   = (unsigned short*)d_ws;                 // 4*25*12*4096 = 4,915,200
    unsigned short* wT   = xT + (size_t)4915200;                  // 12*12*128*32 =   589,824
    unsigned short* wT3  = wT + (size_t)589824;                   // 3*16*128*32  =   196,608
    unsigned short* qkvT = wT3 + (size_t)196608;                  // 3*4*8*3136*64 = 19,267,584
    unsigned short* aoT  = qkvT + (size_t)(3 * QKV_T);            // 4*49*16*2048 =  6,422,528

    // one merged preprocessing dispatch: 2400 cvtT_x blocks + 384 cvt_w blocks
    cvt_all<<<dim3(2784), 256, 0, stream>>>(x, Wq, Wkv, Wo, xT, wT, wT3);

    gemm1<<<dim3(25, 12, 4), 256, 0, stream>>>(xT, wT, qkvT);
    natt2<<<dim3(49, 8, 4), 256, 0, stream>>>(qkvT, aoT);
    gemm3<<<dim3(49, 3, 4), 256, 0, stream>>>(aoT, wT3, bo, out);
}